// Round 5
// baseline (249.717 us; speedup 1.0000x reference)
//
#include <hip/hip_runtime.h>
#include <hip/hip_bf16.h>

// Problem constants
#define BATCH 32
#define LTOT 4096
#define CCH 64
#define NFFT 16
#define HOP 4
#define NF 9            // n_fft/2+1
#define T_FR 1025       // 1 + L/HOP
#define T_ROWS 1032     // padded rows in mag workspace (rows >= 1025 zeroed)
#define ICH 576         // C * NF
#define OCH 512
#define TY 1023         // conv output length
#define OUTW 128

typedef __attribute__((ext_vector_type(8))) _Float16 half8;
typedef __attribute__((ext_vector_type(4))) float floatx4;

// cos(n*pi/8), sin(n*pi/8) for n = 0..15 — compile-time twiddles; all DFT
// coefficients are C16/S16[(f*j)&15]. Full unroll -> fp32 immediates in v_fma.
__device__ constexpr float C16[16] = {
    1.0f,  0.923879533f,  0.707106781f,  0.382683432f,  0.0f, -0.382683432f,
   -0.707106781f, -0.923879533f, -1.0f, -0.923879533f, -0.707106781f,
   -0.382683432f,  0.0f,  0.382683432f,  0.707106781f,  0.923879533f};
__device__ constexpr float S16[16] = {
    0.0f,  0.382683432f,  0.707106781f,  0.923879533f,  1.0f,  0.923879533f,
    0.707106781f,  0.382683432f,  0.0f, -0.382683432f, -0.707106781f,
   -0.923879533f, -1.0f, -0.923879533f, -0.707106781f, -0.382683432f};

// ---------------------------------------------------------------------------
// Kernel 1: STFT magnitude.  x [B, L, C] fp32 -> m_ws [b][t][f*64+c] fp16.
// i-axis permutation (f-major) shared with wrepack; stores lane-contiguous.
// block = 256 threads = 64 c x 4 t; grid = (T_ROWS/4, B)
// ---------------------------------------------------------------------------
__global__ __launch_bounds__(256) void stft_kernel(const float* __restrict__ x,
                                                   _Float16* __restrict__ m_ws) {
  const int b = blockIdx.y;
  const int t0 = blockIdx.x * 4;
  const int tid = threadIdx.x;

  __shared__ float xs[28 * 64];    // frames for 4 t values: 4*4+12 = 28 rows of x

  // stage x rows l0 .. l0+27 with reflect padding
  const int l0 = t0 * HOP - 8;
  const float* xb = x + (size_t)b * LTOT * CCH;
#pragma unroll
  for (int it = 0; it < 7; ++it) {
    int e = it * 256 + tid;
    int r = e >> 6, c = e & 63;
    int l = l0 + r;
    if (l < 0) l = -l;
    if (l >= LTOT) l = 2 * LTOT - 2 - l;
    xs[r * 64 + c] = xb[(size_t)l * CCH + c];
  }
  __syncthreads();

  const int c = tid & 63, tq = tid >> 6;
  const int t = t0 + tq;
  if (t >= T_ROWS) return;
  _Float16* out = m_ws + ((size_t)b * T_ROWS + t) * ICH + c;  // + f*64 per bin
  if (t >= T_FR) {
#pragma unroll
    for (int f = 0; f < NF; ++f) out[f * 64] = (_Float16)0.0f;
    return;
  }
  float wx[16];
#pragma unroll
  for (int j = 0; j < 16; ++j) {
    // periodic hann: 0.5*(1 - cos(pi*j/8)) — compile-time constant
    wx[j] = xs[(tq * 4 + j) * 64 + c] * (0.5f * (1.0f - C16[j]));
  }
#pragma unroll
  for (int f = 0; f < NF; ++f) {
    float re = 0.0f, im = 0.0f;
#pragma unroll
    for (int j = 0; j < 16; ++j) {
      re += wx[j] * C16[(f * j) & 15];
      im -= wx[j] * S16[(f * j) & 15];
    }
    out[f * 64] = (_Float16)sqrtf(re * re + im * im);
  }
}

// ---------------------------------------------------------------------------
// Kernel 2: weight repack fp32 [O=512][I=576][K=3] -> fp16 wk[k][o][f*64+c]
// (same i-axis permutation as stft: src i = c*9+f -> dst f*64+c)
// ---------------------------------------------------------------------------
__global__ __launch_bounds__(256) void wrepack_kernel(const float* __restrict__ w,
                                                      _Float16* __restrict__ wk) {
  int idx = blockIdx.x * 256 + threadIdx.x;   // o*576 + i
  if (idx >= OCH * ICH) return;
  int o = idx / ICH, i = idx - o * ICH;
  int c = i / 9, f = i - c * 9;
  const float* src = w + (size_t)o * (ICH * 3) + i * 3;
  const size_t dst = (size_t)o * ICH + f * 64 + c;
#pragma unroll
  for (int k = 0; k < 3; ++k)
    wk[(size_t)k * OCH * ICH + dst] = (_Float16)src[k];
}

// ---------------------------------------------------------------------------
// Kernel 2b: out[b][w][o] = bias[o]  (GEMM epilogue atomically adds pooled y)
// ---------------------------------------------------------------------------
__global__ __launch_bounds__(512) void init_out_kernel(const float* __restrict__ bias,
                                                       float* __restrict__ out) {
  out[((size_t)blockIdx.y * OUTW + blockIdx.x) * OCH + threadIdx.x] =
      bias[threadIdx.x];
}

// ---------------------------------------------------------------------------
// Kernel 3: conv-as-GEMM with global_load_lds width=16 staging + XOR swizzle,
// and FUSED bias+adaptive-pool epilogue (no y buffer, no pool kernel).
//   y[t][o] = sum_{k=0..2} sum_i wk[k][o][i] * m[b][t+k][i]
// t belongs to pool bins w0=(128t)/1023 and w1=(128(t+1)-1)/1023 (overlap<=1).
// Tile reduces acc into <=18 LDS bin rows (ds_add_f32), then one scaled
// global atomicAdd per (bin, o) into out (pre-initialized with bias).
// grid = (8 t-tiles, 4 o-tiles, 32 batches), block 256 (4 waves, 2x2).
// ---------------------------------------------------------------------------
#define BM 128
#define BN 128
#define BK 64
#define NBINS 18

__device__ __forceinline__ void async_copy16(const _Float16* g, _Float16* l) {
  __builtin_amdgcn_global_load_lds(
      (const __attribute__((address_space(1))) unsigned int*)g,
      (__attribute__((address_space(3))) unsigned int*)l, 16, 0, 0);
}

__global__ __launch_bounds__(256, 4) void conv_gemm_kernel(
    const _Float16* __restrict__ m_ws, const _Float16* __restrict__ wk,
    float* __restrict__ out) {
  const int b = blockIdx.z;
  const int o0 = blockIdx.y * BM;
  const int t0 = blockIdx.x * BN;
  const int tid = threadIdx.x;
  const int wave = tid >> 6, lane = tid & 63;
  const int wm = wave >> 1, wn = wave & 1;       // 2x2 wave grid

  __shared__ _Float16 as[BM * BK];   // 16 KB, rows of 64 halves (128 B)
  __shared__ _Float16 bs[BN * BK];   // 16 KB

  floatx4 acc[4][4];
#pragma unroll
  for (int mt = 0; mt < 4; ++mt)
#pragma unroll
    for (int nt = 0; nt < 4; ++nt)
      acc[mt][nt] = (floatx4)0.0f;

  const _Float16* mb = m_ws + (size_t)b * T_ROWS * ICH;
  const int frow = lane & 15;          // non-K fragment index
  const int quad = lane >> 4;
  const int l7 = lane & 7;

  // staging geometry: one global_load_lds covers 8 rows (64 lanes x 16 B).
  const int srow = lane >> 3;                  // 0..7
  const int schunk = l7 ^ srow;                // swizzled source 16B-chunk
  const int ssrc_off = srow * ICH + schunk * 8;

  for (int kb = 0; kb < 27; ++kb) {
    const int ksh = kb / 9;                    // conv tap 0..2
    const int i0 = (kb - ksh * 9) * BK;        // (kb%9)*64
    const _Float16* ag = wk + (size_t)ksh * OCH * ICH + (size_t)o0 * ICH + i0;
    const _Float16* bg = mb + (size_t)(t0 + ksh) * ICH + i0;

#pragma unroll
    for (int it = 0; it < 4; ++it) {
      const int seg = wave * 4 + it;           // 0..15, 8 rows each
      async_copy16(ag + (size_t)(seg * 8) * ICH + ssrc_off, &as[seg * 512]);
      async_copy16(bg + (size_t)(seg * 8) * ICH + ssrc_off, &bs[seg * 512]);
    }
    __syncthreads();   // drains vmcnt (global_load_lds) + barrier

#pragma unroll
    for (int kk2 = 0; kk2 < 2; ++kk2) {
      const int jj = kk2 * 4 + quad;           // K 16B-chunk index 0..7
      const int coff = ((jj ^ l7) << 3);       // swizzled half offset in row
      half8 af[4], bf[4];
#pragma unroll
      for (int mt = 0; mt < 4; ++mt)
        af[mt] = *(const half8*)(&as[(wm * 64 + mt * 16 + frow) * 64 + coff]);
#pragma unroll
      for (int nt = 0; nt < 4; ++nt)
        bf[nt] = *(const half8*)(&bs[(wn * 64 + nt * 16 + frow) * 64 + coff]);
      // first operand = t-fragment => D row (quad*4+reg) = t, D col (lane&15) = o
#pragma unroll
      for (int mt = 0; mt < 4; ++mt)
#pragma unroll
        for (int nt = 0; nt < 4; ++nt)
          acc[mt][nt] = __builtin_amdgcn_mfma_f32_16x16x32_f16(bf[nt], af[mt],
                                                               acc[mt][nt], 0, 0, 0);
    }
    __syncthreads();
  }

  // ---- fused bias+pool epilogue (reuses as/bs LDS as bin accumulators) ----
  float* bins = (float*)as;                     // NBINS*128 floats = 9 KB < 16 KB
  const int wbase = (t0 << 7) / 1023;
#pragma unroll
  for (int i = 0; i < NBINS * 128 / 256; ++i) bins[i * 256 + tid] = 0.0f;
  __syncthreads();

  const int col = lane & 15;
#pragma unroll
  for (int mt = 0; mt < 4; ++mt) {
    const int olc = wm * 64 + mt * 16 + col;    // o_local 0..127
#pragma unroll
    for (int nt = 0; nt < 4; ++nt) {
      const int tb = t0 + wn * 64 + nt * 16 + quad * 4;
#pragma unroll
      for (int r = 0; r < 4; ++r) {
        const int t = tb + r;
        if (t < TY) {
          const float v = acc[mt][nt][r];
          const int w0 = (t << 7) / 1023;
          const int w1 = (((t + 1) << 7) - 1) / 1023;
          atomicAdd(&bins[(w0 - wbase) * 128 + olc], v);
          if (w1 > w0) atomicAdd(&bins[(w1 - wbase) * 128 + olc], v);
        }
      }
    }
  }
  __syncthreads();

  const int max_t = (t0 + BN - 1 < TY - 1) ? t0 + BN - 1 : TY - 1;
  const int wtop = (((max_t + 1) << 7) - 1) / 1023;
  const int ol = tid & 127, wofs = tid >> 7;    // 2 bins per pass
  float* outb = out + (size_t)b * OUTW * OCH + o0;
  for (int wi = wbase + wofs; wi <= wtop; wi += 2) {
    const int st = (wi * TY) >> 7;
    const int en = ((wi + 1) * TY + 127) >> 7;
    const float v = bins[(wi - wbase) * 128 + ol] / (float)(en - st);
    atomicAdd(&outb[(size_t)wi * OCH + ol], v);
  }
}

// ---------------------------------------------------------------------------
extern "C" void kernel_launch(void* const* d_in, const int* in_sizes, int n_in,
                              void* d_out, int out_size, void* d_ws, size_t ws_size,
                              hipStream_t stream) {
  const float* x = (const float*)d_in[0];       // [32, 4096, 64]
  const float* weight = (const float*)d_in[1];  // [512, 576, 3]
  const float* bias = (const float*)d_in[2];    // [512]
  float* out = (float*)d_out;                   // [32, 128, 512]

  char* ws = (char*)d_ws;
  const size_t m_bytes = (size_t)BATCH * T_ROWS * ICH * sizeof(_Float16);  // 38,043,648
  _Float16* m_ws = (_Float16*)ws;
  _Float16* wk = (_Float16*)(ws + m_bytes);     // 3*512*576 fp16 = 1,769,472

  hipLaunchKernelGGL(stft_kernel, dim3(T_ROWS / 4, BATCH), dim3(256), 0, stream,
                     x, m_ws);
  hipLaunchKernelGGL(wrepack_kernel, dim3((OCH * ICH + 255) / 256), dim3(256), 0,
                     stream, weight, wk);
  hipLaunchKernelGGL(init_out_kernel, dim3(OUTW, BATCH), dim3(512), 0, stream,
                     bias, out);
  hipLaunchKernelGGL(conv_gemm_kernel, dim3(8, 4, BATCH), dim3(256), 0, stream,
                     m_ws, wk, out);
}

// Round 6
// 166.533 us; speedup vs baseline: 1.4995x; 1.4995x over previous
//
#include <hip/hip_runtime.h>
#include <hip/hip_bf16.h>

// Problem constants
#define BATCH 32
#define LTOT 4096
#define CCH 64
#define NFFT 16
#define HOP 4
#define NF 9            // n_fft/2+1
#define T_FR 1025       // 1 + L/HOP
#define T_ROWS 1032     // padded rows in mag workspace (rows >= 1025 zeroed)
#define ICH 576         // C * NF
#define OCH 512
#define TY 1023         // conv output length
#define OUTW 128

typedef __attribute__((ext_vector_type(8))) _Float16 half8;
typedef __attribute__((ext_vector_type(4))) float floatx4;

// cos/sin(n*pi/8) for n = 0..15 — compile-time twiddles; fully-unrolled
// constant indexing folds 0/±1 coefficients away entirely.
__device__ constexpr float C16[16] = {
    1.0f,  0.923879533f,  0.707106781f,  0.382683432f,  0.0f, -0.382683432f,
   -0.707106781f, -0.923879533f, -1.0f, -0.923879533f, -0.707106781f,
   -0.382683432f,  0.0f,  0.382683432f,  0.707106781f,  0.923879533f};
__device__ constexpr float S16[16] = {
    0.0f,  0.382683432f,  0.707106781f,  0.923879533f,  1.0f,  0.923879533f,
    0.707106781f,  0.382683432f,  0.0f, -0.382683432f, -0.707106781f,
   -0.923879533f, -1.0f, -0.923879533f, -0.707106781f, -0.382683432f};

// ---------------------------------------------------------------------------
// Kernel 1: STFT magnitude.  x [B, L, C] fp32 -> m_ws [b][t][f*64+c] fp16.
// Real-input DFT folded via j <-> 16-j symmetry: s[j]=wx[j]+wx[16-j] feeds
// cos terms, d[j]=wx[j]-wx[16-j] feeds sin terms (im sign irrelevant for
// magnitude) -> 14 MACs per bin instead of 32.
// i-axis permutation (f-major) shared with wrepack; stores lane-contiguous.
// block = 256 threads = 64 c x 4 t; grid = (T_ROWS/4, B)
// ---------------------------------------------------------------------------
__global__ __launch_bounds__(256) void stft_kernel(const float* __restrict__ x,
                                                   _Float16* __restrict__ m_ws) {
  const int b = blockIdx.y;
  const int t0 = blockIdx.x * 4;
  const int tid = threadIdx.x;

  __shared__ float xs[28 * 64];    // frames for 4 t values: 4*4+12 = 28 rows of x

  // stage x rows l0 .. l0+27 with reflect padding
  const int l0 = t0 * HOP - 8;
  const float* xb = x + (size_t)b * LTOT * CCH;
#pragma unroll
  for (int it = 0; it < 7; ++it) {
    int e = it * 256 + tid;
    int r = e >> 6, c = e & 63;
    int l = l0 + r;
    if (l < 0) l = -l;
    if (l >= LTOT) l = 2 * LTOT - 2 - l;
    xs[r * 64 + c] = xb[(size_t)l * CCH + c];
  }
  __syncthreads();

  const int c = tid & 63, tq = tid >> 6;
  const int t = t0 + tq;
  if (t >= T_ROWS) return;
  _Float16* out = m_ws + ((size_t)b * T_ROWS + t) * ICH + c;  // + f*64 per bin
  if (t >= T_FR) {
#pragma unroll
    for (int f = 0; f < NF; ++f) out[f * 64] = (_Float16)0.0f;
    return;
  }
  float wx[16];
#pragma unroll
  for (int j = 0; j < 16; ++j) {
    // periodic hann: 0.5*(1 - cos(pi*j/8)) — compile-time constant
    wx[j] = xs[(tq * 4 + j) * 64 + c] * (0.5f * (1.0f - C16[j]));
  }
  float s[8], d[8];
#pragma unroll
  for (int j = 1; j < 8; ++j) {
    s[j] = wx[j] + wx[16 - j];
    d[j] = wx[j] - wx[16 - j];
  }
#pragma unroll
  for (int f = 0; f < NF; ++f) {
    float re = wx[0] + ((f & 1) ? -wx[8] : wx[8]);
    float im = 0.0f;
#pragma unroll
    for (int j = 1; j < 8; ++j) {
      re += s[j] * C16[(f * j) & 15];
      im += d[j] * S16[(f * j) & 15];
    }
    out[f * 64] = (_Float16)sqrtf(re * re + im * im);
  }
}

// ---------------------------------------------------------------------------
// Kernel 2: weight repack fp32 [O=512][I=576][K=3] -> fp16 wk[k][o][f*64+c]
// (same i-axis permutation as stft: src i = c*9+f -> dst f*64+c)
// ---------------------------------------------------------------------------
__global__ __launch_bounds__(256) void wrepack_kernel(const float* __restrict__ w,
                                                      _Float16* __restrict__ wk) {
  int idx = blockIdx.x * 256 + threadIdx.x;   // o*576 + i
  if (idx >= OCH * ICH) return;
  int o = idx / ICH, i = idx - o * ICH;
  int c = i / 9, f = i - c * 9;
  const float* src = w + (size_t)o * (ICH * 3) + i * 3;
  const size_t dst = (size_t)o * ICH + f * 64 + c;
#pragma unroll
  for (int k = 0; k < 3; ++k)
    wk[(size_t)k * OCH * ICH + dst] = (_Float16)src[k];
}

// ---------------------------------------------------------------------------
// Kernel 3: conv-as-GEMM with global_load_lds width=16 staging + XOR swizzle.
// (R4 version — known 63.9 us, MfmaUtil ~40%, zero bank conflicts.
//  R5's fused-pool epilogue with global atomics regressed 2.3x: latency-bound
//  atomic/CAS chains after the K-loop cannot be hidden. Do NOT re-fuse with
//  atomics.)
//   y[t][o] = sum_{k=0..2} sum_i wk[k][o][i] * m[b][t+k][i]
// grid = (8 t-tiles, 4 o-tiles, 32 batches), block 256 (4 waves, 2x2).
// ---------------------------------------------------------------------------
#define BM 128
#define BN 128
#define BK 64

__device__ __forceinline__ void async_copy16(const _Float16* g, _Float16* l) {
  __builtin_amdgcn_global_load_lds(
      (const __attribute__((address_space(1))) unsigned int*)g,
      (__attribute__((address_space(3))) unsigned int*)l, 16, 0, 0);
}

__global__ __launch_bounds__(256, 4) void conv_gemm_kernel(
    const _Float16* __restrict__ m_ws, const _Float16* __restrict__ wk,
    float* __restrict__ y) {
  const int b = blockIdx.z;
  const int o0 = blockIdx.y * BM;
  const int t0 = blockIdx.x * BN;
  const int tid = threadIdx.x;
  const int wave = tid >> 6, lane = tid & 63;
  const int wm = wave >> 1, wn = wave & 1;       // 2x2 wave grid

  __shared__ _Float16 as[BM * BK];   // 16 KB, rows of 64 halves (128 B)
  __shared__ _Float16 bs[BN * BK];   // 16 KB

  floatx4 acc[4][4];
#pragma unroll
  for (int mt = 0; mt < 4; ++mt)
#pragma unroll
    for (int nt = 0; nt < 4; ++nt)
      acc[mt][nt] = (floatx4)0.0f;

  const _Float16* mb = m_ws + (size_t)b * T_ROWS * ICH;
  const int frow = lane & 15;          // non-K fragment index
  const int quad = lane >> 4;
  const int l7 = lane & 7;

  // staging geometry: one global_load_lds covers 8 rows (64 lanes x 16 B).
  const int srow = lane >> 3;                  // 0..7
  const int schunk = l7 ^ srow;                // swizzled source 16B-chunk
  const int ssrc_off = srow * ICH + schunk * 8;

  for (int kb = 0; kb < 27; ++kb) {
    const int ksh = kb / 9;                    // conv tap 0..2
    const int i0 = (kb - ksh * 9) * BK;        // (kb%9)*64
    const _Float16* ag = wk + (size_t)ksh * OCH * ICH + (size_t)o0 * ICH + i0;
    const _Float16* bg = mb + (size_t)(t0 + ksh) * ICH + i0;

#pragma unroll
    for (int it = 0; it < 4; ++it) {
      const int seg = wave * 4 + it;           // 0..15, 8 rows each
      async_copy16(ag + (size_t)(seg * 8) * ICH + ssrc_off, &as[seg * 512]);
      async_copy16(bg + (size_t)(seg * 8) * ICH + ssrc_off, &bs[seg * 512]);
    }
    __syncthreads();   // drains vmcnt (global_load_lds) + barrier

#pragma unroll
    for (int kk2 = 0; kk2 < 2; ++kk2) {
      const int jj = kk2 * 4 + quad;           // K 16B-chunk index 0..7
      const int coff = ((jj ^ l7) << 3);       // swizzled half offset in row
      half8 af[4], bf[4];
#pragma unroll
      for (int mt = 0; mt < 4; ++mt)
        af[mt] = *(const half8*)(&as[(wm * 64 + mt * 16 + frow) * 64 + coff]);
#pragma unroll
      for (int nt = 0; nt < 4; ++nt)
        bf[nt] = *(const half8*)(&bs[(wn * 64 + nt * 16 + frow) * 64 + coff]);
      // first operand = t-fragment => D row (quad*4+reg) = t, D col (lane&15) = o
#pragma unroll
      for (int mt = 0; mt < 4; ++mt)
#pragma unroll
        for (int nt = 0; nt < 4; ++nt)
          acc[mt][nt] = __builtin_amdgcn_mfma_f32_16x16x32_f16(bf[nt], af[mt],
                                                               acc[mt][nt], 0, 0, 0);
    }
    __syncthreads();
  }

  // epilogue: y[b][t][o], t stride padded to 1024 rows of OCH floats
  const int col = lane & 15;
  float* yb = y + (((size_t)b << 10)) * OCH;
#pragma unroll
  for (int mt = 0; mt < 4; ++mt) {
    const int o = o0 + wm * 64 + mt * 16 + col;
#pragma unroll
    for (int nt = 0; nt < 4; ++nt) {
      const int tb = t0 + wn * 64 + nt * 16 + quad * 4;
#pragma unroll
      for (int r = 0; r < 4; ++r) {
        yb[(size_t)(tb + r) * OCH + o] = acc[mt][nt][r];
      }
    }
  }
}

// ---------------------------------------------------------------------------
// Kernel 4: adaptive avg pool (overlapping torch bins) + bias, float4 wide.
// out[b][w][o] = bias[o] + mean_{t in bin(w)} y[b][t][o]
// y layout [b][t(pad 1024)][o] -> coalesced float4 reads along o.
// grid = (128 w, 32 b), block = 128 (each thread: 4 consecutive o)
// ---------------------------------------------------------------------------
__global__ __launch_bounds__(128) void pool_kernel(const float* __restrict__ y,
                                                   const float* __restrict__ bias,
                                                   float* __restrict__ out) {
  const int b = blockIdx.y, w = blockIdx.x;
  const int o = threadIdx.x * 4;
  const int start = (w * TY) >> 7;
  const int end = ((w + 1) * TY + 127) >> 7;
  const float* yb = y + (((size_t)b << 10)) * OCH;
  floatx4 s = (floatx4)0.0f;
  for (int t = start; t < end; ++t)
    s += *(const floatx4*)(yb + (size_t)t * OCH + o);
  const float inv = 1.0f / (float)(end - start);
  floatx4 r = s * inv + *(const floatx4*)(bias + o);
  *(floatx4*)(out + ((size_t)b * OUTW + w) * OCH + o) = r;
}

// ---------------------------------------------------------------------------
extern "C" void kernel_launch(void* const* d_in, const int* in_sizes, int n_in,
                              void* d_out, int out_size, void* d_ws, size_t ws_size,
                              hipStream_t stream) {
  const float* x = (const float*)d_in[0];       // [32, 4096, 64]
  const float* weight = (const float*)d_in[1];  // [512, 576, 3]
  const float* bias = (const float*)d_in[2];    // [512]
  float* out = (float*)d_out;                   // [32, 128, 512]

  char* ws = (char*)d_ws;
  const size_t m_bytes = (size_t)BATCH * T_ROWS * ICH * sizeof(_Float16);  // 38,043,648
  const size_t w_bytes = (size_t)3 * OCH * ICH * sizeof(_Float16);         // 1,769,472
  _Float16* m_ws = (_Float16*)ws;
  _Float16* wk = (_Float16*)(ws + m_bytes);
  float* y = (float*)(ws + m_bytes + w_bytes);  // [32][1024][512] fp32 = 67,108,864

  hipLaunchKernelGGL(stft_kernel, dim3(T_ROWS / 4, BATCH), dim3(256), 0, stream,
                     x, m_ws);
  hipLaunchKernelGGL(wrepack_kernel, dim3((OCH * ICH + 255) / 256), dim3(256), 0,
                     stream, weight, wk);
  hipLaunchKernelGGL(conv_gemm_kernel, dim3(8, 4, BATCH), dim3(256), 0, stream,
                     m_ws, wk, y);
  hipLaunchKernelGGL(pool_kernel, dim3(OUTW, BATCH), dim3(128), 0, stream,
                     y, bias, out);
}

// Round 7
// 154.600 us; speedup vs baseline: 1.6152x; 1.0772x over previous
//
#include <hip/hip_runtime.h>
#include <hip/hip_bf16.h>

// Problem constants
#define BATCH 32
#define LTOT 4096
#define CCH 64
#define NFFT 16
#define HOP 4
#define NF 9            // n_fft/2+1
#define T_FR 1025       // 1 + L/HOP
#define T_ROWS 1032     // padded rows in mag workspace (rows >= 1025 zeroed)
#define ICH 576         // C * NF
#define OCH 512
#define TY 1023         // conv output length
#define OUTW 128

typedef __attribute__((ext_vector_type(8))) _Float16 half8;
typedef __attribute__((ext_vector_type(4))) float floatx4;

// cos/sin(n*pi/8) for n = 0..15 — compile-time twiddles; fully-unrolled
// constant indexing folds 0/±1 coefficients away entirely.
__device__ constexpr float C16[16] = {
    1.0f,  0.923879533f,  0.707106781f,  0.382683432f,  0.0f, -0.382683432f,
   -0.707106781f, -0.923879533f, -1.0f, -0.923879533f, -0.707106781f,
   -0.382683432f,  0.0f,  0.382683432f,  0.707106781f,  0.923879533f};
__device__ constexpr float S16[16] = {
    0.0f,  0.382683432f,  0.707106781f,  0.923879533f,  1.0f,  0.923879533f,
    0.707106781f,  0.382683432f,  0.0f, -0.382683432f, -0.707106781f,
   -0.923879533f, -1.0f, -0.923879533f, -0.707106781f, -0.382683432f};

// ---------------------------------------------------------------------------
// Kernel 1: STFT magnitude.  x [B, L, C] fp32 -> m_ws [b][t][f*64+c] fp16.
// Real-input DFT folded via j <-> 16-j symmetry (14 MACs/bin vs 32).
// i-axis permutation (f-major) shared with wrepack; stores lane-contiguous.
// block = 256 threads = 64 c x 4 t; grid = (T_ROWS/4, B)
// ---------------------------------------------------------------------------
__global__ __launch_bounds__(256) void stft_kernel(const float* __restrict__ x,
                                                   _Float16* __restrict__ m_ws) {
  const int b = blockIdx.y;
  const int t0 = blockIdx.x * 4;
  const int tid = threadIdx.x;

  __shared__ float xs[28 * 64];    // frames for 4 t values: 4*4+12 = 28 rows of x

  // stage x rows l0 .. l0+27 with reflect padding
  const int l0 = t0 * HOP - 8;
  const float* xb = x + (size_t)b * LTOT * CCH;
#pragma unroll
  for (int it = 0; it < 7; ++it) {
    int e = it * 256 + tid;
    int r = e >> 6, c = e & 63;
    int l = l0 + r;
    if (l < 0) l = -l;
    if (l >= LTOT) l = 2 * LTOT - 2 - l;
    xs[r * 64 + c] = xb[(size_t)l * CCH + c];
  }
  __syncthreads();

  const int c = tid & 63, tq = tid >> 6;
  const int t = t0 + tq;
  if (t >= T_ROWS) return;
  _Float16* out = m_ws + ((size_t)b * T_ROWS + t) * ICH + c;  // + f*64 per bin
  if (t >= T_FR) {
#pragma unroll
    for (int f = 0; f < NF; ++f) out[f * 64] = (_Float16)0.0f;
    return;
  }
  float wx[16];
#pragma unroll
  for (int j = 0; j < 16; ++j) {
    // periodic hann: 0.5*(1 - cos(pi*j/8)) — compile-time constant
    wx[j] = xs[(tq * 4 + j) * 64 + c] * (0.5f * (1.0f - C16[j]));
  }
  float s[8], d[8];
#pragma unroll
  for (int j = 1; j < 8; ++j) {
    s[j] = wx[j] + wx[16 - j];
    d[j] = wx[j] - wx[16 - j];
  }
#pragma unroll
  for (int f = 0; f < NF; ++f) {
    float re = wx[0] + ((f & 1) ? -wx[8] : wx[8]);
    float im = 0.0f;
#pragma unroll
    for (int j = 1; j < 8; ++j) {
      re += s[j] * C16[(f * j) & 15];
      im += d[j] * S16[(f * j) & 15];
    }
    out[f * 64] = (_Float16)sqrtf(re * re + im * im);
  }
}

// ---------------------------------------------------------------------------
// Kernel 2: weight repack fp32 [O=512][I=576][K=3] -> fp16 wk[k][o][f*64+c]
// (same i-axis permutation as stft: src i = c*9+f -> dst f*64+c)
// ---------------------------------------------------------------------------
__global__ __launch_bounds__(256) void wrepack_kernel(const float* __restrict__ w,
                                                      _Float16* __restrict__ wk) {
  int idx = blockIdx.x * 256 + threadIdx.x;   // o*576 + i
  if (idx >= OCH * ICH) return;
  int o = idx / ICH, i = idx - o * ICH;
  int c = i / 9, f = i - c * 9;
  const float* src = w + (size_t)o * (ICH * 3) + i * 3;
  const size_t dst = (size_t)o * ICH + f * 64 + c;
#pragma unroll
  for (int k = 0; k < 3; ++k)
    wk[(size_t)k * OCH * ICH + dst] = (_Float16)src[k];
}

// ---------------------------------------------------------------------------
// Kernel 3: conv-as-GEMM, global_load_lds width=16 + XOR swizzle, with
// TAP-SHARED B staging: the 3 conv taps read B-tiles differing by one row,
// so per i-block we stage B rows t0..t0+129 ONCE (17 segments incl. a
// 2-row partial) and run 3 taps reading LDS at row offset ksh. Staged volume
// per block: 9*(17+3*16) segs = 585 KB vs 864 KB tap-redundant (-32%).
// Read-side swizzle uses (frow+ksh)&7 since B fragment rows are no longer
// 8-aligned. Output y is fp16 (halves write drain + pool read traffic).
// NOTE (R5): never use global/LDS per-element atomics in the epilogue —
// latency-bound chains after the K-loop regressed 2.3x.
// grid = (8 t-tiles, 4 o-tiles, 32 batches), block 256 (4 waves, 2x2).
// ---------------------------------------------------------------------------
#define BM 128
#define BN 128
#define BK 64

__device__ __forceinline__ void async_copy16(const _Float16* g, _Float16* l) {
  __builtin_amdgcn_global_load_lds(
      (const __attribute__((address_space(1))) unsigned int*)g,
      (__attribute__((address_space(3))) unsigned int*)l, 16, 0, 0);
}

__global__ __launch_bounds__(256, 4) void conv_gemm_kernel(
    const _Float16* __restrict__ m_ws, const _Float16* __restrict__ wk,
    _Float16* __restrict__ y) {
  const int b = blockIdx.z;
  const int o0 = blockIdx.y * BM;
  const int t0 = blockIdx.x * BN;
  const int tid = threadIdx.x;
  const int wave = tid >> 6, lane = tid & 63;
  const int wm = wave >> 1, wn = wave & 1;       // 2x2 wave grid

  __shared__ _Float16 as[BM * BK];        // 16 KB   (A: weights, tap-current)
  __shared__ _Float16 bs[(BN + 2) * BK];  // 16.25 KB (B: mag rows t0..t0+129)

  floatx4 acc[4][4];
#pragma unroll
  for (int mt = 0; mt < 4; ++mt)
#pragma unroll
    for (int nt = 0; nt < 4; ++nt)
      acc[mt][nt] = (floatx4)0.0f;

  const _Float16* mb = m_ws + (size_t)b * T_ROWS * ICH;
  const int frow = lane & 15;          // non-K fragment index
  const int quad = lane >> 4;
  const int l7 = lane & 7;

  // staging geometry: one global_load_lds covers 8 rows (64 lanes x 16 B).
  // lane -> row_in_seg = lane>>3, src chunk = (lane&7) ^ (lane>>3) (swizzle:
  // slot c of row r holds source chunk c ^ (r&7)).
  const int srow = lane >> 3;                  // 0..7
  const int ssrc_off = srow * ICH + (l7 ^ srow) * 8;

  for (int ib = 0; ib < 9; ++ib) {
    const int i0 = ib * 64;
    const _Float16* bg = mb + (size_t)t0 * ICH + i0;

    // stage B rows t0 .. t0+129 (16 full segs + one 2-row partial)
#pragma unroll
    for (int it = 0; it < 4; ++it) {
      const int seg = wave * 4 + it;           // 0..15, 8 rows each
      async_copy16(bg + (size_t)(seg * 8) * ICH + ssrc_off, &bs[seg * 512]);
    }
    if (tid < 16)  // rows 128,129: lane>>3 in {0,1}; same swizzle formula
      async_copy16(bg + (size_t)128 * ICH + ssrc_off, &bs[128 * 64]);

#pragma unroll
    for (int ksh = 0; ksh < 3; ++ksh) {
      // stage A (weights for tap ksh)
      const _Float16* ag = wk + ((size_t)ksh * OCH + o0) * ICH + i0;
#pragma unroll
      for (int it = 0; it < 4; ++it) {
        const int seg = wave * 4 + it;
        async_copy16(ag + (size_t)(seg * 8) * ICH + ssrc_off, &as[seg * 512]);
      }
      __syncthreads();   // drains vmcnt (B once per ib + A) + barrier

      const int rb7 = (frow + ksh) & 7;        // B read-swizzle row parity
#pragma unroll
      for (int kk2 = 0; kk2 < 2; ++kk2) {
        const int jj = kk2 * 4 + quad;         // K 16B-chunk index 0..7
        const int coffA = ((jj ^ l7) << 3);
        const int coffB = ((jj ^ rb7) << 3);
        half8 af[4], bf[4];
#pragma unroll
        for (int mt = 0; mt < 4; ++mt)
          af[mt] = *(const half8*)(&as[(wm * 64 + mt * 16 + frow) * 64 + coffA]);
#pragma unroll
        for (int nt = 0; nt < 4; ++nt)
          bf[nt] = *(const half8*)(
              &bs[(wn * 64 + nt * 16 + frow + ksh) * 64 + coffB]);
        // first operand = t-fragment => D row (quad*4+reg) = t, D col = o
#pragma unroll
        for (int mt = 0; mt < 4; ++mt)
#pragma unroll
          for (int nt = 0; nt < 4; ++nt)
            acc[mt][nt] = __builtin_amdgcn_mfma_f32_16x16x32_f16(
                bf[nt], af[mt], acc[mt][nt], 0, 0, 0);
      }
      __syncthreads();
    }
  }

  // epilogue: y[b][t][o] fp16, t stride padded to 1024 rows of OCH halves
  const int col = lane & 15;
  _Float16* yb = y + (((size_t)b << 10)) * OCH;
#pragma unroll
  for (int mt = 0; mt < 4; ++mt) {
    const int o = o0 + wm * 64 + mt * 16 + col;
#pragma unroll
    for (int nt = 0; nt < 4; ++nt) {
      const int tb = t0 + wn * 64 + nt * 16 + quad * 4;
#pragma unroll
      for (int r = 0; r < 4; ++r) {
        const int t = tb + r;
        if (t < TY) yb[(size_t)t * OCH + o] = (_Float16)acc[mt][nt][r];
      }
    }
  }
}

// ---------------------------------------------------------------------------
// Kernel 4: adaptive avg pool (overlapping torch bins) + bias, half8 wide.
// out[b][w][o] = bias[o] + mean_{t in bin(w)} y[b][t][o]
// y fp16 [b][t(pad 1024)][o] -> coalesced 16B reads along o.
// grid = (128 w, 32 b), block = 64 (each thread: 8 consecutive o)
// ---------------------------------------------------------------------------
__global__ __launch_bounds__(64) void pool_kernel(const _Float16* __restrict__ y,
                                                  const float* __restrict__ bias,
                                                  float* __restrict__ out) {
  const int b = blockIdx.y, w = blockIdx.x;
  const int o = threadIdx.x * 8;
  const int start = (w * TY) >> 7;
  const int end = ((w + 1) * TY + 127) >> 7;
  const _Float16* yb = y + (((size_t)b << 10)) * OCH;
  float s[8];
#pragma unroll
  for (int i = 0; i < 8; ++i) s[i] = 0.0f;
  for (int t = start; t < end; ++t) {
    half8 v = *(const half8*)(yb + (size_t)t * OCH + o);
#pragma unroll
    for (int i = 0; i < 8; ++i) s[i] += (float)v[i];
  }
  const float inv = 1.0f / (float)(end - start);
  float* op = out + ((size_t)b * OUTW + w) * OCH + o;
  floatx4 r0, r1;
#pragma unroll
  for (int i = 0; i < 4; ++i) r0[i] = s[i] * inv + bias[o + i];
#pragma unroll
  for (int i = 0; i < 4; ++i) r1[i] = s[4 + i] * inv + bias[o + 4 + i];
  *(floatx4*)(op) = r0;
  *(floatx4*)(op + 4) = r1;
}

// ---------------------------------------------------------------------------
extern "C" void kernel_launch(void* const* d_in, const int* in_sizes, int n_in,
                              void* d_out, int out_size, void* d_ws, size_t ws_size,
                              hipStream_t stream) {
  const float* x = (const float*)d_in[0];       // [32, 4096, 64]
  const float* weight = (const float*)d_in[1];  // [512, 576, 3]
  const float* bias = (const float*)d_in[2];    // [512]
  float* out = (float*)d_out;                   // [32, 128, 512]

  char* ws = (char*)d_ws;
  const size_t m_bytes = (size_t)BATCH * T_ROWS * ICH * sizeof(_Float16);  // 38,043,648
  const size_t w_bytes = (size_t)3 * OCH * ICH * sizeof(_Float16);         // 1,769,472
  _Float16* m_ws = (_Float16*)ws;
  _Float16* wk = (_Float16*)(ws + m_bytes);
  _Float16* y = (_Float16*)(ws + m_bytes + w_bytes);  // [32][1024][512] fp16 = 33.5 MB

  hipLaunchKernelGGL(stft_kernel, dim3(T_ROWS / 4, BATCH), dim3(256), 0, stream,
                     x, m_ws);
  hipLaunchKernelGGL(wrepack_kernel, dim3((OCH * ICH + 255) / 256), dim3(256), 0,
                     stream, weight, wk);
  hipLaunchKernelGGL(conv_gemm_kernel, dim3(8, 4, BATCH), dim3(256), 0, stream,
                     m_ws, wk, y);
  hipLaunchKernelGGL(pool_kernel, dim3(OUTW, BATCH), dim3(64), 0, stream,
                     y, bias, out);
}